// Round 1
// baseline (277.362 us; speedup 1.0000x reference)
//
#include <hip/hip_runtime.h>

// ---------- types ----------
using bf16x8 = __attribute__((ext_vector_type(8))) short;
using v8bf   = __attribute__((ext_vector_type(8))) __bf16;
using f32x4  = __attribute__((ext_vector_type(4))) float;

typedef const __attribute__((address_space(1))) void GASV;
typedef __attribute__((address_space(3))) void LASV;

// MFMA wrapper: ROCm builtin signature may take short8 or __bf16 x8 depending
// on toolchain; SFINAE picks whichever compiles.
template <typename V>
__device__ __forceinline__ auto mfma_bf16_impl(V a, V b, f32x4 c, int)
    -> decltype(__builtin_amdgcn_mfma_f32_16x16x32_bf16(a, b, c, 0, 0, 0)) {
  return __builtin_amdgcn_mfma_f32_16x16x32_bf16(a, b, c, 0, 0, 0);
}
template <typename V>
__device__ __forceinline__ f32x4 mfma_bf16_impl(V a, V b, f32x4 c, long) {
  return __builtin_amdgcn_mfma_f32_16x16x32_bf16(
      __builtin_bit_cast(v8bf, a), __builtin_bit_cast(v8bf, b), c, 0, 0, 0);
}
__device__ __forceinline__ f32x4 MFMA(bf16x8 a, bf16x8 b, f32x4 c) {
  return mfma_bf16_impl(a, b, c, 0);
}

__device__ __forceinline__ void async_lds16(const void* g, void* l) {
  __builtin_amdgcn_global_load_lds((GASV*)g, (LASV*)l, 16, 0, 0);
}

__device__ __forceinline__ unsigned short f2bf(float x) {
  unsigned u = __float_as_uint(x);
  u = u + 0x7fffu + ((u >> 16) & 1u);
  return (unsigned short)(u >> 16);
}
__device__ __forceinline__ float bf2f(unsigned short s) {
  return __uint_as_float(((unsigned)s) << 16);
}

#define LOG2E 1.4426950408889634f

// ---------- converters ----------
__global__ __launch_bounds__(256) void k_cvt_x(const float4* __restrict__ x,
                                               ushort4* __restrict__ o) {
  int i = blockIdx.x * 256 + threadIdx.x;
  float4 v = x[i];
  ushort4 p;
  p.x = f2bf(v.x); p.y = f2bf(v.y); p.z = f2bf(v.z); p.w = f2bf(v.w);
  o[i] = p;
}

// out[z][n][k] = W_z[k][n], bf16
__global__ __launch_bounds__(256) void k_transpose_w(
    const float* __restrict__ w0, const float* __restrict__ w1,
    const float* __restrict__ w2, const float* __restrict__ w3,
    const float* __restrict__ w4, unsigned short* __restrict__ out) {
  __shared__ float t[32][33];
  const int z = blockIdx.z;
  const float* W = (z == 0) ? w0 : (z == 1) ? w1 : (z == 2) ? w2 : (z == 3) ? w3 : w4;
  unsigned short* o = out + (size_t)z * (1u << 20);
  const int bx = blockIdx.x * 32, by = blockIdx.y * 32;
  const int tx = threadIdx.x, ty = threadIdx.y;
#pragma unroll
  for (int i = 0; i < 4; ++i)
    t[ty + i * 8][tx] = W[(size_t)(by + ty + i * 8) * 1024 + bx + tx];
  __syncthreads();
#pragma unroll
  for (int i = 0; i < 4; ++i)
    o[(size_t)(bx + ty + i * 8) * 1024 + by + tx] = f2bf(t[tx][ty + i * 8]);
}

// ---------- 128x128 NT GEMM core (K=1024, bf16, m97 pattern) ----------
__device__ __forceinline__ void gemm_core(const unsigned short* __restrict__ A,
                                          const unsigned short* __restrict__ Bt,
                                          unsigned short* ldsA,
                                          unsigned short* ldsB,
                                          f32x4 acc[4][4]) {
  const int tid = threadIdx.x;
  const int w = tid >> 6, lane = tid & 63;
  const int lane15 = lane & 15, quad = lane >> 4;
  const int wm = w >> 1, wn = w & 1;
  for (int ko = 0; ko < 32; ++ko) {
    __syncthreads();
#pragma unroll
    for (int i = 0; i < 2; ++i) {
      const int p = i * 256 + tid;
      const int r = p >> 2, q = p & 3;
      const int goff = r * 1024 + ko * 32 + q * 8;
      async_lds16(A + goff, ldsA + (i * 256 + w * 64) * 8);
      async_lds16(Bt + goff, ldsB + (i * 256 + w * 64) * 8);
    }
    __syncthreads();
    bf16x8 af[4], bfr[4];
#pragma unroll
    for (int t = 0; t < 4; ++t) {
      af[t]  = *(const bf16x8*)&ldsA[(wm * 64 + t * 16 + lane15) * 32 + quad * 8];
      bfr[t] = *(const bf16x8*)&ldsB[(wn * 64 + t * 16 + lane15) * 32 + quad * 8];
    }
#pragma unroll
    for (int mi = 0; mi < 4; ++mi)
#pragma unroll
      for (int ni = 0; ni < 4; ++ni)
        acc[mi][ni] = MFMA(af[mi], bfr[ni], acc[mi][ni]);
  }
}

#define GEMM_PROLOGUE()                                              \
  __shared__ unsigned short ldsA[128 * 32];                          \
  __shared__ unsigned short ldsB[128 * 32];                          \
  f32x4 acc[4][4];                                                   \
  {                                                                  \
    f32x4 z_ = {0.f, 0.f, 0.f, 0.f};                                 \
    for (int i_ = 0; i_ < 4; ++i_)                                   \
      for (int j_ = 0; j_ < 4; ++j_) acc[i_][j_] = z_;               \
  }

#define GEMM_EPI_IDX()                                               \
  const int tid = threadIdx.x, w = tid >> 6, lane = tid & 63;        \
  const int lane15 = lane & 15, quad = lane >> 4;                    \
  const int wm = w >> 1, wn = w & 1;                                 \
  const int r0 = tm + wm * 64 + quad * 4;                            \
  const int c0 = tn + wn * 64 + lane15;

// z: 0=pre(silu,+bpre)  1=q(*log2e/8)  2=k  3=v(transposed per head)
__global__ __launch_bounds__(256) void k_gemm_qkvpre(
    const unsigned short* __restrict__ xb, const unsigned short* __restrict__ wt,
    const float* __restrict__ bpre, unsigned short* __restrict__ pre,
    unsigned short* __restrict__ qb, unsigned short* __restrict__ kb,
    unsigned short* __restrict__ vt) {
  const int z = blockIdx.z;
  const int tm = blockIdx.y * 128, tn = blockIdx.x * 128;
  GEMM_PROLOGUE();
  gemm_core(xb + (size_t)tm * 1024, wt + (size_t)z * (1u << 20) + (size_t)tn * 1024,
            ldsA, ldsB, acc);
  GEMM_EPI_IDX();
  if (z == 0) {
#pragma unroll
    for (int mi = 0; mi < 4; ++mi)
#pragma unroll
      for (int ni = 0; ni < 4; ++ni) {
        const int cg = c0 + ni * 16;
        const float bb = bpre[cg];
#pragma unroll
        for (int rr = 0; rr < 4; ++rr) {
          const int m = r0 + mi * 16 + rr;
          float v = acc[mi][ni][rr] + bb;
          v = v / (1.0f + __expf(-v));
          pre[(size_t)m * 1024 + cg] = f2bf(v);
        }
      }
  } else if (z == 1) {
#pragma unroll
    for (int mi = 0; mi < 4; ++mi)
#pragma unroll
      for (int ni = 0; ni < 4; ++ni) {
        const int cg = c0 + ni * 16;
#pragma unroll
        for (int rr = 0; rr < 4; ++rr)
          qb[(size_t)(r0 + mi * 16 + rr) * 1024 + cg] =
              f2bf(acc[mi][ni][rr] * (LOG2E / 8.0f));
      }
  } else if (z == 2) {
#pragma unroll
    for (int mi = 0; mi < 4; ++mi)
#pragma unroll
      for (int ni = 0; ni < 4; ++ni) {
        const int cg = c0 + ni * 16;
#pragma unroll
        for (int rr = 0; rr < 4; ++rr)
          kb[(size_t)(r0 + mi * 16 + rr) * 1024 + cg] = f2bf(acc[mi][ni][rr]);
      }
  } else {
#pragma unroll
    for (int mi = 0; mi < 4; ++mi) {
      const int m = r0 + mi * 16;  // base of 4 consecutive seq positions
      const int bb_ = m >> 10, nseq = m & 1023;
#pragma unroll
      for (int ni = 0; ni < 4; ++ni) {
        const int cg = c0 + ni * 16;
        const int hh = cg >> 6, dd = cg & 63;
        ushort4 pk;
        pk.x = f2bf(acc[mi][ni][0]); pk.y = f2bf(acc[mi][ni][1]);
        pk.z = f2bf(acc[mi][ni][2]); pk.w = f2bf(acc[mi][ni][3]);
        *(ushort4*)&vt[(size_t)(((bb_ * 16 + hh) << 6) + dd) * 1024 + nseq] = pk;
      }
    }
  }
}

// Lg[b][i][j] = (pi*log2e/32) * dot(pre[b,i,:], pre[b,j,:])
__global__ __launch_bounds__(256) void k_gemm_logits(
    const unsigned short* __restrict__ pre, const float* __restrict__ pi,
    unsigned short* __restrict__ lg) {
  const int bz = blockIdx.z;
  const unsigned short* base = pre + ((size_t)bz << 20);
  const int tm = blockIdx.y * 128, tn = blockIdx.x * 128;
  GEMM_PROLOGUE();
  gemm_core(base + (size_t)tm * 1024, base + (size_t)tn * 1024, ldsA, ldsB, acc);
  const float sc = pi[0] * (LOG2E / 32.0f);
  GEMM_EPI_IDX();
#pragma unroll
  for (int mi = 0; mi < 4; ++mi)
#pragma unroll
    for (int ni = 0; ni < 4; ++ni) {
      const int cg = c0 + ni * 16;
#pragma unroll
      for (int rr = 0; rr < 4; ++rr)
        lg[((size_t)bz << 20) + (size_t)(r0 + mi * 16 + rr) * 1024 + cg] =
            f2bf(acc[mi][ni][rr] * sc);
    }
}

// out = ao @ Wproj^T(pretransposed) + bproj + x
__global__ __launch_bounds__(256) void k_gemm_out(
    const unsigned short* __restrict__ ao, const unsigned short* __restrict__ wtp,
    const float* __restrict__ bproj, const float* __restrict__ xres,
    float* __restrict__ out) {
  const int tm = blockIdx.y * 128, tn = blockIdx.x * 128;
  GEMM_PROLOGUE();
  gemm_core(ao + (size_t)tm * 1024, wtp + (size_t)tn * 1024, ldsA, ldsB, acc);
  GEMM_EPI_IDX();
#pragma unroll
  for (int mi = 0; mi < 4; ++mi)
#pragma unroll
    for (int ni = 0; ni < 4; ++ni) {
      const int cg = c0 + ni * 16;
      const float bb = bproj[cg];
#pragma unroll
      for (int rr = 0; rr < 4; ++rr) {
        const size_t idx = (size_t)(r0 + mi * 16 + rr) * 1024 + cg;
        out[idx] = acc[mi][ni][rr] + bb + xres[idx];
      }
    }
}

// ---------- fused flash attention with logit bias ----------
// grid (8,16,4): 128 q-rows per block (32 per wave), KV chunks of 128.
__global__ __launch_bounds__(256) void k_attn(
    const unsigned short* __restrict__ qb, const unsigned short* __restrict__ kb,
    const unsigned short* __restrict__ vt, const unsigned short* __restrict__ lg,
    unsigned short* __restrict__ ao) {
  __shared__ unsigned short ldsK[128 * 64];    // [kv][k], chunk-swizzled
  __shared__ unsigned short ldsV[64 * 128];    // [d][kv], chunk-swizzled
  __shared__ unsigned short ldsP[4][32 * 128]; // per-wave P, col-block swizzled
  const int b = blockIdx.z, h = blockIdx.y, q0 = blockIdx.x * 128;
  const int tid = threadIdx.x, w = tid >> 6, lane = tid & 63;
  const int lane15 = lane & 15, quad = lane >> 4;
  const int qw = q0 + w * 32;

  bf16x8 qf[2][2];
#pragma unroll
  for (int mt = 0; mt < 2; ++mt) {
    const unsigned short* qrow =
        qb + (size_t)((b << 10) + qw + mt * 16 + lane15) * 1024 + (h << 6);
    qf[mt][0] = *(const bf16x8*)(qrow + quad * 8);
    qf[mt][1] = *(const bf16x8*)(qrow + 32 + quad * 8);
  }
  float mrow[2][4], lrow[2][4];
  f32x4 o[2][4];
  {
    f32x4 z_ = {0.f, 0.f, 0.f, 0.f};
#pragma unroll
    for (int mt = 0; mt < 2; ++mt)
#pragma unroll
      for (int rr = 0; rr < 4; ++rr) {
        mrow[mt][rr] = -__builtin_inff();
        lrow[mt][rr] = 0.f;
        o[mt][rr] = z_;
      }
  }

  for (int c = 0; c < 8; ++c) {
    const int kv0 = c * 128;
    __syncthreads();
#pragma unroll
    for (int i = 0; i < 4; ++i) {
      const int p = i * 256 + tid;
      {  // K: [128 kv][64 k]; slot s in row holds chunk s^(r&7)
        const int r = p >> 3, cc = (p & 7) ^ (r & 7);
        async_lds16(kb + (size_t)((b << 10) + kv0 + r) * 1024 + (h << 6) + cc * 8,
                    ldsK + (i * 256 + w * 64) * 8);
      }
      {  // V^T: [64 d][128 kv]; slot s holds chunk s^(r&15)
        const int r = p >> 4, cc = (p & 15) ^ (r & 15);
        async_lds16(vt + (size_t)(((b * 16 + h) << 6) + r) * 1024 + kv0 + cc * 8,
                    ldsV + (i * 256 + w * 64) * 8);
      }
    }
    __syncthreads();

    // S = q k^T (q pre-scaled by log2e/8)
    f32x4 s[2][8];
#pragma unroll
    for (int ni = 0; ni < 8; ++ni) {
      const int row = ni * 16 + lane15;
      const int ch0 = (quad) ^ (row & 7);
      const int ch1 = (4 + quad) ^ (row & 7);
      bf16x8 k0 = *(const bf16x8*)&ldsK[row * 64 + ch0 * 8];
      bf16x8 k1 = *(const bf16x8*)&ldsK[row * 64 + ch1 * 8];
#pragma unroll
      for (int mt = 0; mt < 2; ++mt) {
        f32x4 t = {0.f, 0.f, 0.f, 0.f};
        t = MFMA(qf[mt][0], k0, t);
        t = MFMA(qf[mt][1], k1, t);
        s[mt][ni] = t;
      }
    }
    // + bias logits (already scaled by pi*log2e/32)
#pragma unroll
    for (int mt = 0; mt < 2; ++mt) {
      const unsigned short* lgrow =
          lg + ((size_t)b << 20) + (size_t)(qw + mt * 16 + quad * 4) * 1024 + kv0;
#pragma unroll
      for (int rr = 0; rr < 4; ++rr)
#pragma unroll
        for (int ni = 0; ni < 8; ++ni)
          s[mt][ni][rr] += bf2f(lgrow[rr * 1024 + ni * 16 + lane15]);
    }
    // online softmax (exp2 domain) + P to LDS
#pragma unroll
    for (int mt = 0; mt < 2; ++mt) {
      float alpha[4];
#pragma unroll
      for (int rr = 0; rr < 4; ++rr) {
        float mx = s[mt][0][rr];
#pragma unroll
        for (int ni = 1; ni < 8; ++ni) mx = fmaxf(mx, s[mt][ni][rr]);
        mx = fmaxf(mx, __shfl_xor(mx, 1));
        mx = fmaxf(mx, __shfl_xor(mx, 2));
        mx = fmaxf(mx, __shfl_xor(mx, 4));
        mx = fmaxf(mx, __shfl_xor(mx, 8));
        const float mn = fmaxf(mrow[mt][rr], mx);
        alpha[rr] = exp2f(mrow[mt][rr] - mn);
        mrow[mt][rr] = mn;
        lrow[mt][rr] *= alpha[rr];
      }
#pragma unroll
      for (int n4 = 0; n4 < 4; ++n4)
#pragma unroll
        for (int rr = 0; rr < 4; ++rr) o[mt][n4][rr] *= alpha[rr];
      float rs[4] = {0.f, 0.f, 0.f, 0.f};
#pragma unroll
      for (int ni = 0; ni < 8; ++ni) {
        const int colsw = ((ni ^ quad) << 4) + lane15;  // col-block ^= (row>>2)&3
#pragma unroll
        for (int rr = 0; rr < 4; ++rr) {
          const float pv = exp2f(s[mt][ni][rr] - mrow[mt][rr]);
          rs[rr] += pv;
          ldsP[w][(mt * 16 + quad * 4 + rr) * 128 + colsw] = f2bf(pv);
        }
      }
#pragma unroll
      for (int rr = 0; rr < 4; ++rr) {
        rs[rr] += __shfl_xor(rs[rr], 1);
        rs[rr] += __shfl_xor(rs[rr], 2);
        rs[rr] += __shfl_xor(rs[rr], 4);
        rs[rr] += __shfl_xor(rs[rr], 8);
        lrow[mt][rr] += rs[rr];
      }
    }
    // O += P V   (P read back swizzled; same-wave LDS dep handled by compiler)
    const int Lsw = (lane15 >> 2) & 3;
#pragma unroll
    for (int ks = 0; ks < 4; ++ks) {
      const int cb = ((ks * 2 + (quad >> 1)) ^ Lsw) * 16 + (quad & 1) * 8;
      bf16x8 pf0 = *(const bf16x8*)&ldsP[w][(0 + lane15) * 128 + cb];
      bf16x8 pf1 = *(const bf16x8*)&ldsP[w][(16 + lane15) * 128 + cb];
#pragma unroll
      for (int n4 = 0; n4 < 4; ++n4) {
        const int row = n4 * 16 + lane15;
        const int ch = (ks * 4 + quad) ^ (row & 15);
        bf16x8 vf = *(const bf16x8*)&ldsV[row * 128 + ch * 8];
        o[0][n4] = MFMA(pf0, vf, o[0][n4]);
        o[1][n4] = MFMA(pf1, vf, o[1][n4]);
      }
    }
  }
  // normalize + store attn output in [B*N, H*Dh] bf16
#pragma unroll
  for (int mt = 0; mt < 2; ++mt) {
    float rinv[4];
#pragma unroll
    for (int rr = 0; rr < 4; ++rr) rinv[rr] = 1.0f / lrow[mt][rr];
#pragma unroll
    for (int n4 = 0; n4 < 4; ++n4) {
      const int cg = (h << 6) + n4 * 16 + lane15;
#pragma unroll
      for (int rr = 0; rr < 4; ++rr) {
        const int m = (b << 10) + qw + mt * 16 + quad * 4 + rr;
        ao[(size_t)m * 1024 + cg] = f2bf(o[mt][n4][rr] * rinv[rr]);
      }
    }
  }
}

// ---------- launch ----------
extern "C" void kernel_launch(void* const* d_in, const int* in_sizes, int n_in,
                              void* d_out, int out_size, void* d_ws, size_t ws_size,
                              hipStream_t stream) {
  const float* x     = (const float*)d_in[0];
  const float* Wq    = (const float*)d_in[1];
  const float* Wk    = (const float*)d_in[2];
  const float* Wv    = (const float*)d_in[3];
  const float* Wproj = (const float*)d_in[4];
  const float* bproj = (const float*)d_in[5];
  const float* Wpre  = (const float*)d_in[6];
  const float* bpre  = (const float*)d_in[7];
  const float* pi    = (const float*)d_in[8];
  float* out = (float*)d_out;
  char* ws = (char*)d_ws;

  unsigned short* xb  = (unsigned short*)(ws);               // 8 MB (later: lg)
  unsigned short* wt  = (unsigned short*)(ws + (8u << 20));  // 10 MB (pre,q,k,v,proj transposed)
  unsigned short* pre = (unsigned short*)(ws + (18u << 20)); // 8 MB (later: ao)
  unsigned short* qb  = (unsigned short*)(ws + (26u << 20)); // 8 MB
  unsigned short* kb  = (unsigned short*)(ws + (34u << 20)); // 8 MB
  unsigned short* vt  = (unsigned short*)(ws + (42u << 20)); // 8 MB  -> total 50 MB
  unsigned short* lg  = xb;   // xb dead after k_gemm_qkvpre
  unsigned short* ao  = pre;  // pre dead after k_gemm_logits

  k_cvt_x<<<dim3(4096), dim3(256), 0, stream>>>((const float4*)x, (ushort4*)xb);
  k_transpose_w<<<dim3(32, 32, 5), dim3(32, 8), 0, stream>>>(Wpre, Wq, Wk, Wv, Wproj, wt);
  k_gemm_qkvpre<<<dim3(8, 32, 4), dim3(256), 0, stream>>>(xb, wt, bpre, pre, qb, kb, vt);
  k_gemm_logits<<<dim3(8, 8, 4), dim3(256), 0, stream>>>(pre, pi, lg);
  k_attn<<<dim3(8, 16, 4), dim3(256), 0, stream>>>(qb, kb, vt, lg, ao);
  k_gemm_out<<<dim3(8, 32, 1), dim3(256), 0, stream>>>(ao, wt + 4 * (1u << 20), bproj, x, out);
}

// Round 2
// 247.431 us; speedup vs baseline: 1.1210x; 1.1210x over previous
//
#include <hip/hip_runtime.h>

// ---------- types ----------
using bf16x8 = __attribute__((ext_vector_type(8))) short;
using v8bf   = __attribute__((ext_vector_type(8))) __bf16;
using f32x4  = __attribute__((ext_vector_type(4))) float;

typedef const __attribute__((address_space(1))) void GASV;
typedef __attribute__((address_space(3))) void LASV;

template <typename V>
__device__ __forceinline__ auto mfma_bf16_impl(V a, V b, f32x4 c, int)
    -> decltype(__builtin_amdgcn_mfma_f32_16x16x32_bf16(a, b, c, 0, 0, 0)) {
  return __builtin_amdgcn_mfma_f32_16x16x32_bf16(a, b, c, 0, 0, 0);
}
template <typename V>
__device__ __forceinline__ f32x4 mfma_bf16_impl(V a, V b, f32x4 c, long) {
  return __builtin_amdgcn_mfma_f32_16x16x32_bf16(
      __builtin_bit_cast(v8bf, a), __builtin_bit_cast(v8bf, b), c, 0, 0, 0);
}
__device__ __forceinline__ f32x4 MFMA(bf16x8 a, bf16x8 b, f32x4 c) {
  return mfma_bf16_impl(a, b, c, 0);
}

__device__ __forceinline__ void async_lds16(const void* g, void* l) {
  __builtin_amdgcn_global_load_lds((GASV*)g, (LASV*)l, 16, 0, 0);
}

__device__ __forceinline__ unsigned short f2bf(float x) {
  unsigned u = __float_as_uint(x);
  u = u + 0x7fffu + ((u >> 16) & 1u);
  return (unsigned short)(u >> 16);
}
__device__ __forceinline__ float bf2f(unsigned short s) {
  return __uint_as_float(((unsigned)s) << 16);
}

#define LOG2E 1.4426950408889634f

// ---------- converters ----------
__global__ __launch_bounds__(256) void k_cvt_x(const float4* __restrict__ x,
                                               ushort4* __restrict__ o) {
  int i = blockIdx.x * 256 + threadIdx.x;
  float4 v = x[i];
  ushort4 p;
  p.x = f2bf(v.x); p.y = f2bf(v.y); p.z = f2bf(v.z); p.w = f2bf(v.w);
  o[i] = p;
}

// out[z][n][k] = W_z[k][n], bf16
__global__ __launch_bounds__(256) void k_transpose_w(
    const float* __restrict__ w0, const float* __restrict__ w1,
    const float* __restrict__ w2, const float* __restrict__ w3,
    const float* __restrict__ w4, unsigned short* __restrict__ out) {
  __shared__ float t[32][33];
  const int z = blockIdx.z;
  const float* W = (z == 0) ? w0 : (z == 1) ? w1 : (z == 2) ? w2 : (z == 3) ? w3 : w4;
  unsigned short* o = out + (size_t)z * (1u << 20);
  const int bx = blockIdx.x * 32, by = blockIdx.y * 32;
  const int tx = threadIdx.x, ty = threadIdx.y;
#pragma unroll
  for (int i = 0; i < 4; ++i)
    t[ty + i * 8][tx] = W[(size_t)(by + ty + i * 8) * 1024 + bx + tx];
  __syncthreads();
#pragma unroll
  for (int i = 0; i < 4; ++i)
    o[(size_t)(bx + ty + i * 8) * 1024 + by + tx] = f2bf(t[tx][ty + i * 8]);
}

// ---------- templated NT GEMM core (K=1024): tile (MI*32) x (NI*32) ----------
template <int MI, int NI>
__device__ __forceinline__ void gemm_core_t(const unsigned short* __restrict__ A,
                                            const unsigned short* __restrict__ Bt,
                                            unsigned short* ldsA,
                                            unsigned short* ldsB,
                                            f32x4 acc[MI][NI]) {
  const int tid = threadIdx.x;
  const int w = tid >> 6, lane = tid & 63;
  const int lane15 = lane & 15, quad = lane >> 4;
  const int wm = w >> 1, wn = w & 1;
  for (int ko = 0; ko < 32; ++ko) {
    __syncthreads();
#pragma unroll
    for (int i = 0; i < MI / 2; ++i) {
      const int p = i * 256 + tid;
      async_lds16(A + (p >> 2) * 1024 + ko * 32 + (p & 3) * 8,
                  ldsA + (i * 256 + w * 64) * 8);
    }
#pragma unroll
    for (int i = 0; i < NI / 2; ++i) {
      const int p = i * 256 + tid;
      async_lds16(Bt + (p >> 2) * 1024 + ko * 32 + (p & 3) * 8,
                  ldsB + (i * 256 + w * 64) * 8);
    }
    __syncthreads();
    bf16x8 af[MI], bfr[NI];
#pragma unroll
    for (int t = 0; t < MI; ++t)
      af[t] = *(const bf16x8*)&ldsA[(wm * (MI * 16) + t * 16 + lane15) * 32 + quad * 8];
#pragma unroll
    for (int t = 0; t < NI; ++t)
      bfr[t] = *(const bf16x8*)&ldsB[(wn * (NI * 16) + t * 16 + lane15) * 32 + quad * 8];
#pragma unroll
    for (int mi = 0; mi < MI; ++mi)
#pragma unroll
      for (int ni = 0; ni < NI; ++ni)
        acc[mi][ni] = MFMA(af[mi], bfr[ni], acc[mi][ni]);
  }
}

#define GEMM_PROLOGUE(MI_, NI_)                                      \
  __shared__ unsigned short ldsA[(MI_)*32 * 32];                     \
  __shared__ unsigned short ldsB[(NI_)*32 * 32];                     \
  f32x4 acc[MI_][NI_];                                               \
  {                                                                  \
    f32x4 z_ = {0.f, 0.f, 0.f, 0.f};                                 \
    for (int i_ = 0; i_ < (MI_); ++i_)                               \
      for (int j_ = 0; j_ < (NI_); ++j_) acc[i_][j_] = z_;           \
  }

#define GEMM_EPI_IDX(MI_, NI_)                                       \
  const int tid = threadIdx.x, w = tid >> 6, lane = tid & 63;        \
  const int lane15 = lane & 15, quad = lane >> 4;                    \
  const int wm = w >> 1, wn = w & 1;                                 \
  const int r0 = tm + wm * ((MI_)*16) + quad * 4;                    \
  const int c0 = tn + wn * ((NI_)*16) + lane15;

// z: 0=pre(silu,+bpre)  1=q(*log2e/8)  2=k  3=v(transposed per head)
__global__ __launch_bounds__(256) void k_gemm_qkvpre(
    const unsigned short* __restrict__ xb, const unsigned short* __restrict__ wt,
    const float* __restrict__ bpre, unsigned short* __restrict__ pre,
    unsigned short* __restrict__ qb, unsigned short* __restrict__ kb,
    unsigned short* __restrict__ vt) {
  const int z = blockIdx.z;
  const int tm = blockIdx.y * 128, tn = blockIdx.x * 128;
  GEMM_PROLOGUE(4, 4);
  gemm_core_t<4, 4>(xb + (size_t)tm * 1024,
                    wt + (size_t)z * (1u << 20) + (size_t)tn * 1024, ldsA, ldsB, acc);
  GEMM_EPI_IDX(4, 4);
  if (z == 0) {
#pragma unroll
    for (int mi = 0; mi < 4; ++mi)
#pragma unroll
      for (int ni = 0; ni < 4; ++ni) {
        const int cg = c0 + ni * 16;
        const float bb = bpre[cg];
#pragma unroll
        for (int rr = 0; rr < 4; ++rr) {
          const int m = r0 + mi * 16 + rr;
          float v = acc[mi][ni][rr] + bb;
          v = v / (1.0f + __expf(-v));
          pre[(size_t)m * 1024 + cg] = f2bf(v);
        }
      }
  } else if (z == 1) {
#pragma unroll
    for (int mi = 0; mi < 4; ++mi)
#pragma unroll
      for (int ni = 0; ni < 4; ++ni) {
        const int cg = c0 + ni * 16;
#pragma unroll
        for (int rr = 0; rr < 4; ++rr)
          qb[(size_t)(r0 + mi * 16 + rr) * 1024 + cg] =
              f2bf(acc[mi][ni][rr] * (LOG2E / 8.0f));
      }
  } else if (z == 2) {
#pragma unroll
    for (int mi = 0; mi < 4; ++mi)
#pragma unroll
      for (int ni = 0; ni < 4; ++ni) {
        const int cg = c0 + ni * 16;
#pragma unroll
        for (int rr = 0; rr < 4; ++rr)
          kb[(size_t)(r0 + mi * 16 + rr) * 1024 + cg] = f2bf(acc[mi][ni][rr]);
      }
  } else {
#pragma unroll
    for (int mi = 0; mi < 4; ++mi) {
      const int m = r0 + mi * 16;
      const int bb_ = m >> 10, nseq = m & 1023;
#pragma unroll
      for (int ni = 0; ni < 4; ++ni) {
        const int cg = c0 + ni * 16;
        const int hh = cg >> 6, dd = cg & 63;
        ushort4 pk;
        pk.x = f2bf(acc[mi][ni][0]); pk.y = f2bf(acc[mi][ni][1]);
        pk.z = f2bf(acc[mi][ni][2]); pk.w = f2bf(acc[mi][ni][3]);
        *(ushort4*)&vt[(size_t)(((bb_ * 16 + hh) << 6) + dd) * 1024 + nseq] = pk;
      }
    }
  }
}

// Lg[b][i][j] = (pi*log2e/32) * dot(pre[b,i,:], pre[b,j,:])  -- 64x128 tiles
__global__ __launch_bounds__(256) void k_gemm_logits(
    const unsigned short* __restrict__ pre, const float* __restrict__ pi,
    unsigned short* __restrict__ lg) {
  const int bz = blockIdx.z;
  const unsigned short* base = pre + ((size_t)bz << 20);
  const int tm = blockIdx.y * 64, tn = blockIdx.x * 128;
  GEMM_PROLOGUE(2, 4);
  gemm_core_t<2, 4>(base + (size_t)tm * 1024, base + (size_t)tn * 1024, ldsA, ldsB, acc);
  const float sc = pi[0] * (LOG2E / 32.0f);
  GEMM_EPI_IDX(2, 4);
#pragma unroll
  for (int mi = 0; mi < 2; ++mi)
#pragma unroll
    for (int ni = 0; ni < 4; ++ni) {
      const int cg = c0 + ni * 16;
#pragma unroll
      for (int rr = 0; rr < 4; ++rr)
        lg[((size_t)bz << 20) + (size_t)(r0 + mi * 16 + rr) * 1024 + cg] =
            f2bf(acc[mi][ni][rr] * sc);
    }
}

// out = ao @ Wproj(pretransposed) + bproj + x   -- 64x128 tiles
__global__ __launch_bounds__(256) void k_gemm_out(
    const unsigned short* __restrict__ ao, const unsigned short* __restrict__ wtp,
    const float* __restrict__ bproj, const float* __restrict__ xres,
    float* __restrict__ out) {
  const int tm = blockIdx.y * 64, tn = blockIdx.x * 128;
  GEMM_PROLOGUE(2, 4);
  gemm_core_t<2, 4>(ao + (size_t)tm * 1024, wtp + (size_t)tn * 1024, ldsA, ldsB, acc);
  GEMM_EPI_IDX(2, 4);
#pragma unroll
  for (int mi = 0; mi < 2; ++mi)
#pragma unroll
    for (int ni = 0; ni < 4; ++ni) {
      const int cg = c0 + ni * 16;
      const float bb = bproj[cg];
#pragma unroll
      for (int rr = 0; rr < 4; ++rr) {
        const size_t idx = (size_t)(r0 + mi * 16 + rr) * 1024 + cg;
        out[idx] = acc[mi][ni][rr] + bb + xres[idx];
      }
    }
}

// ---------- fused flash attention, S^T = K q^T layout ----------
// grid (16,16,4): 64 q-rows per block (16 per wave), KV chunks of 128.
// S^T C-layout: col(lane15)=q, row(quad*4+rr)=kv -> lg loads are ushort4,
// softmax needs only shfl_xor 16/32, P writes vectorized.
__global__ __launch_bounds__(256, 3) void k_attn(
    const unsigned short* __restrict__ qb, const unsigned short* __restrict__ kb,
    const unsigned short* __restrict__ vt, const unsigned short* __restrict__ lg,
    unsigned short* __restrict__ ao) {
  __shared__ unsigned short ldsK[128 * 64];     // [kv][d], 16B-chunk swz ^(kv&7)
  __shared__ unsigned short ldsV[64 * 128];     // [d][kv], 16B-chunk swz ^(d&15)
  __shared__ unsigned short ldsP[4][16 * 128];  // per-wave [q][kv], swz ^(q&15)
  const int b = blockIdx.z, h = blockIdx.y, q0 = blockIdx.x * 64;
  const int tid = threadIdx.x, w = tid >> 6, lane = tid & 63;
  const int lane15 = lane & 15, quad = lane >> 4;
  const int qw = q0 + w * 16;
  char* Pb = (char*)&ldsP[w][0];

  // q as B-operand: lane holds q[qw+lane15][quad*8 .. +7] (+32)
  bf16x8 qf[2];
  {
    const unsigned short* qrow =
        qb + (size_t)((b << 10) + qw + lane15) * 1024 + (h << 6);
    qf[0] = *(const bf16x8*)(qrow + quad * 8);
    qf[1] = *(const bf16x8*)(qrow + 32 + quad * 8);
  }
  float mcol = -__builtin_inff(), lcol = 0.f;  // per q (=lane15) column state
  f32x4 o[4];  // O[q16][d64]: nt tiles; row=quad*4+rr=q, col=lane15=d
  {
    f32x4 z_ = {0.f, 0.f, 0.f, 0.f};
#pragma unroll
    for (int nt = 0; nt < 4; ++nt) o[nt] = z_;
  }

  for (int c = 0; c < 8; ++c) {
    const int kv0 = c * 128;
    __syncthreads();
#pragma unroll
    for (int i = 0; i < 4; ++i) {
      const int p = i * 256 + tid;
      {  // K [kv][64]: 8 chunks/row
        const int r = p >> 3, cc = (p & 7) ^ (r & 7);
        async_lds16(kb + (size_t)((b << 10) + kv0 + r) * 1024 + (h << 6) + cc * 8,
                    ldsK + (i * 256 + w * 64) * 8);
      }
      {  // V^T [d][128]: 16 chunks/row
        const int r = p >> 4, cc = (p & 15) ^ (r & 15);
        async_lds16(vt + (size_t)(((b * 16 + h) << 6) + r) * 1024 + kv0 + cc * 8,
                    ldsV + (i * 256 + w * 64) * 8);
      }
    }
    // prefetch bias logits (independent of LDS; drained by the barrier)
    uint2 lgv[8];
    {
      const unsigned short* lgrow =
          lg + ((size_t)b << 20) + (size_t)(qw + lane15) * 1024 + kv0 + quad * 4;
#pragma unroll
      for (int mi = 0; mi < 8; ++mi) lgv[mi] = *(const uint2*)(lgrow + mi * 16);
    }
    __syncthreads();

    // S^T = K q^T : A=K tile (m=kv), B=q (n=q)
    f32x4 s[8];
#pragma unroll
    for (int mi = 0; mi < 8; ++mi) {
      const int row = mi * 16 + lane15;
      bf16x8 k0 = *(const bf16x8*)&ldsK[row * 64 + ((quad ^ (row & 7)) << 3)];
      bf16x8 k1 = *(const bf16x8*)&ldsK[row * 64 + (((4 + quad) ^ (row & 7)) << 3)];
      f32x4 t = {0.f, 0.f, 0.f, 0.f};
      t = MFMA(k0, qf[0], t);
      t = MFMA(k1, qf[1], t);
      s[mi] = t;
    }
    // + bias (bf16 pairs -> f32)
#pragma unroll
    for (int mi = 0; mi < 8; ++mi) {
      s[mi][0] += __uint_as_float(lgv[mi].x << 16);
      s[mi][1] += __uint_as_float(lgv[mi].x & 0xffff0000u);
      s[mi][2] += __uint_as_float(lgv[mi].y << 16);
      s[mi][3] += __uint_as_float(lgv[mi].y & 0xffff0000u);
    }
    // online softmax over kv (exp2 domain)
    float mx = s[0][0];
#pragma unroll
    for (int mi = 0; mi < 8; ++mi)
#pragma unroll
      for (int rr = 0; rr < 4; ++rr) mx = fmaxf(mx, s[mi][rr]);
    mx = fmaxf(mx, __shfl_xor(mx, 16));
    mx = fmaxf(mx, __shfl_xor(mx, 32));
    const float mn = fmaxf(mcol, mx);
    const float al = exp2f(mcol - mn);
    mcol = mn;
    float rs = 0.f;
#pragma unroll
    for (int mi = 0; mi < 8; ++mi) {
      const float p0 = exp2f(s[mi][0] - mn), p1 = exp2f(s[mi][1] - mn);
      const float p2 = exp2f(s[mi][2] - mn), p3 = exp2f(s[mi][3] - mn);
      rs += (p0 + p1) + (p2 + p3);
      const unsigned dw0 = ((__float_as_uint(p1) + 0x8000u) & 0xffff0000u) |
                           ((__float_as_uint(p0) + 0x8000u) >> 16);
      const unsigned dw1 = ((__float_as_uint(p3) + 0x8000u) & 0xffff0000u) |
                           ((__float_as_uint(p2) + 0x8000u) >> 16);
      *(uint2*)(Pb + lane15 * 256 + (((2 * mi + (quad >> 1)) ^ lane15) << 4) +
                ((quad & 1) << 3)) = make_uint2(dw0, dw1);
    }
    rs += __shfl_xor(rs, 16);
    rs += __shfl_xor(rs, 32);
    lcol = lcol * al + rs;
    // rescale O (alpha to row layout via bpermute)
    float ar[4];
#pragma unroll
    for (int rr = 0; rr < 4; ++rr) ar[rr] = __shfl(al, quad * 4 + rr);
#pragma unroll
    for (int nt = 0; nt < 4; ++nt)
#pragma unroll
      for (int rr = 0; rr < 4; ++rr) o[nt][rr] *= ar[rr];
    // O += P V : A=P[q][kv] (contig 16B swz), B=V^T rows (contig 16B swz)
#pragma unroll
    for (int ks = 0; ks < 4; ++ks) {
      bf16x8 pf = *(const bf16x8*)(Pb + lane15 * 256 +
                                   ((((ks << 2) + quad) ^ lane15) << 4));
#pragma unroll
      for (int nt = 0; nt < 4; ++nt) {
        const int d = nt * 16 + lane15;
        bf16x8 vf = *(const bf16x8*)&ldsV[d * 128 +
                                          (((ks * 4 + quad) ^ (d & 15)) << 3)];
        o[nt] = MFMA(pf, vf, o[nt]);
      }
    }
  }
  // normalize + store [B*N, H*Dh] bf16
  const float rinv = 1.0f / lcol;
  float rv[4];
#pragma unroll
  for (int rr = 0; rr < 4; ++rr) rv[rr] = __shfl(rinv, quad * 4 + rr);
#pragma unroll
  for (int nt = 0; nt < 4; ++nt) {
    const int cg = (h << 6) + nt * 16 + lane15;
#pragma unroll
    for (int rr = 0; rr < 4; ++rr) {
      const int m = (b << 10) + qw + quad * 4 + rr;
      ao[(size_t)m * 1024 + cg] = f2bf(o[nt][rr] * rv[rr]);
    }
  }
}

// ---------- launch ----------
extern "C" void kernel_launch(void* const* d_in, const int* in_sizes, int n_in,
                              void* d_out, int out_size, void* d_ws, size_t ws_size,
                              hipStream_t stream) {
  const float* x     = (const float*)d_in[0];
  const float* Wq    = (const float*)d_in[1];
  const float* Wk    = (const float*)d_in[2];
  const float* Wv    = (const float*)d_in[3];
  const float* Wproj = (const float*)d_in[4];
  const float* bproj = (const float*)d_in[5];
  const float* Wpre  = (const float*)d_in[6];
  const float* bpre  = (const float*)d_in[7];
  const float* pi    = (const float*)d_in[8];
  float* out = (float*)d_out;
  char* ws = (char*)d_ws;

  unsigned short* xb  = (unsigned short*)(ws);               // 8 MB (later: lg)
  unsigned short* wt  = (unsigned short*)(ws + (8u << 20));  // 10 MB
  unsigned short* pre = (unsigned short*)(ws + (18u << 20)); // 8 MB (later: ao)
  unsigned short* qb  = (unsigned short*)(ws + (26u << 20)); // 8 MB
  unsigned short* kb  = (unsigned short*)(ws + (34u << 20)); // 8 MB
  unsigned short* vt  = (unsigned short*)(ws + (42u << 20)); // 8 MB
  unsigned short* lg  = xb;   // xb dead after k_gemm_qkvpre
  unsigned short* ao  = pre;  // pre dead after k_gemm_logits

  k_cvt_x<<<dim3(4096), dim3(256), 0, stream>>>((const float4*)x, (ushort4*)xb);
  k_transpose_w<<<dim3(32, 32, 5), dim3(32, 8), 0, stream>>>(Wpre, Wq, Wk, Wv, Wproj, wt);
  k_gemm_qkvpre<<<dim3(8, 32, 4), dim3(256), 0, stream>>>(xb, wt, bpre, pre, qb, kb, vt);
  k_gemm_logits<<<dim3(8, 16, 4), dim3(256), 0, stream>>>(pre, pi, lg);
  k_attn<<<dim3(16, 16, 4), dim3(256), 0, stream>>>(qb, kb, vt, lg, ao);
  k_gemm_out<<<dim3(8, 64, 1), dim3(256), 0, stream>>>(ao, wt + 4 * (1u << 20), bproj, x, out);
}